// Round 3
// baseline (417.876 us; speedup 1.0000x reference)
//
#include <hip/hip_runtime.h>
#include <hip/hip_bf16.h>
#include <stdint.h>

typedef __bf16 bf16_t;
typedef bf16_t bf16x8 __attribute__((ext_vector_type(8)));
typedef bf16_t bf16x2 __attribute__((ext_vector_type(2)));
typedef float f32x4 __attribute__((ext_vector_type(4)));

#define E_N 65536
#define T_N 262144
#define CAP 16          // bucket capacity per edge (avg occupancy 4)
#define OVF_MAX T_N     // overflow list can hold every triplet -> always correct

__device__ __forceinline__ float silu_f(float v) {
  return v / (1.0f + __expf(-v));
}

__device__ __forceinline__ int permrow(int n) {
  return (n & ~31) | ((n & 1) << 4) | ((n & 30) >> 1);
}

__device__ __forceinline__ uint32_t pack_bf16(float a, float b) {
  union { bf16x2 h; uint32_t u; } u;
  u.h[0] = (bf16_t)a; u.h[1] = (bf16_t)b;
  return u.u;
}

// ---- async global->LDS DMA (16B per lane) ----
__device__ __forceinline__ void g2l16(const void* g, void* l) {
  __builtin_amdgcn_global_load_lds(
      (const __attribute__((address_space(1))) void*)g,
      (__attribute__((address_space(3))) void*)l, 16, 0, 0);
}

// Copy CHUNKS x 1KB global->LDS with 8 waves; CHUNKS multiple of 8.
template<int CHUNKS>
__device__ __forceinline__ void dma8(const char* g, char* l, int wv, int lane) {
#pragma unroll
  for (int c = 0; c < CHUNKS / 8; ++c) {
    const int off = (c * 8 + wv) * 1024 + lane * 16;
    g2l16(g + off, l + off);
  }
}

#define VMCNT0()   asm volatile("s_waitcnt vmcnt(0)" ::: "memory")
#define S_VMCNT_(n) asm volatile("s_waitcnt vmcnt(" #n ")" ::: "memory")
#define S_VMCNT(n) S_VMCNT_(n)
// raw barrier: LDS visibility via lgkmcnt(0); does NOT drain vmcnt.
#define BARRIER() do {                                          \
    asm volatile("s_waitcnt lgkmcnt(0)" ::: "memory");          \
    __builtin_amdgcn_s_barrier();                               \
    __builtin_amdgcn_sched_barrier(0);                          \
  } while (0)

// ---- MFMA tile GEMM on swizzled stride-128 LDS tiles ----
// element (row,k) stored at row*128 + (((k>>3) ^ (row&15))<<3) + (k&7)
template<int KI, int NTJ>
__device__ __forceinline__ void gemm_tile(const bf16_t* A, const bf16_t* B,
                                          int mb, int nb, int l16, int q,
                                          f32x4 (&acc)[2][NTJ]) {
#pragma unroll
  for (int kt = 0; kt < KI; ++kt) {
    const int sw = ((kt * 4 + q) ^ l16) << 3;
    bf16x8 a0 = *(const bf16x8*)(A + ((mb + l16) << 7) + sw);
    bf16x8 a1 = *(const bf16x8*)(A + ((mb + 16 + l16) << 7) + sw);
#pragma unroll
    for (int tj = 0; tj < NTJ; ++tj) {
      bf16x8 b = *(const bf16x8*)(B + ((nb + tj * 16 + l16) << 7) + sw);
      acc[0][tj] = __builtin_amdgcn_mfma_f32_16x16x32_bf16(a0, b, acc[0][tj], 0, 0, 0);
      acc[1][tj] = __builtin_amdgcn_mfma_f32_16x16x32_bf16(a1, b, acc[1][tj], 0, 0, 0);
    }
  }
}

// Stage fp32 [128][K] tile -> swizzled bf16 LDS with NT threads. C4 = K/4.
template<int C4, int NT>
__device__ __forceinline__ void stage_x(bf16_t* dst, const float* src, int tid) {
  const float4* g = (const float4*)src;
#pragma unroll
  for (int i = tid; i < 128 * C4; i += NT) {
    const int row = i / C4, c4 = i % C4;
    float4 v = g[i];
    bf16_t t[4] = {(bf16_t)v.x, (bf16_t)v.y, (bf16_t)v.z, (bf16_t)v.w};
    *(uint2*)(dst + (row << 7) + ((((c4 >> 1) ^ (row & 15)) << 3) | ((c4 & 1) << 2))) =
        *(const uint2*)t;
  }
}

// =====================  K0: weight preprocessing  =====================
// wm_img[6]  : 32KB perm+swizzle images (Wji, Wkj[1..5])
// wdn_img[5] : 16KB images (Wdown[1..5])
// pset[6]    : 32KB images (Wup, rb1, rb2, Wlin, ra1, ra2)
// wcb        : plain [5][128][8] bf16 fused W_rbf1@W_rbf2
__global__ void prep_kernel(
    const float* __restrict__ W_ji, const float* __restrict__ W_kj,
    const float* __restrict__ W_down, const float* __restrict__ W_up,
    const float* __restrict__ rb1, const float* __restrict__ rb2,
    const float* __restrict__ W_lin, const float* __restrict__ ra1,
    const float* __restrict__ ra2, const float* __restrict__ W_rbf1,
    const float* __restrict__ W_rbf2,
    char* __restrict__ wm_img, char* __restrict__ wdn_img,
    char* __restrict__ pset, bf16_t* __restrict__ wcb)
{
  const int tid = threadIdx.x;
  const int blk = blockIdx.x;

  if (blk < 88) {          // 11 x [128x128] transposed images
    const int item = blk * 256 + tid;
    const int m = item >> 11, w = item & 2047;
    const int n = w >> 4, k8 = w & 15;
    const float* src; char* img;
    if (m == 0)      { src = W_ji;             img = wm_img; }
    else if (m <= 5) { src = W_kj + m * 16384; img = wm_img + m * 32768; }
    else if (m == 6) { src = rb1;   img = pset + 1 * 32768; }
    else if (m == 7) { src = rb2;   img = pset + 2 * 32768; }
    else if (m == 8) { src = W_lin; img = pset + 3 * 32768; }
    else if (m == 9) { src = ra1;   img = pset + 4 * 32768; }
    else             { src = ra2;   img = pset + 5 * 32768; }
    bf16_t t[8];
#pragma unroll
    for (int j = 0; j < 8; ++j) t[j] = (bf16_t)src[(k8 * 8 + j) * 128 + n];
    const int row = permrow(n);
    *(uint4*)((bf16_t*)img + (row << 7) + ((k8 ^ (row & 15)) << 3)) = *(const uint4*)t;
  } else if (blk < 108) {  // 5 x Wdown [64x128] images
    const int item = (blk - 88) * 256 + tid;
    const int m = item >> 10, w = item & 1023;
    const int n = w >> 4, k8 = w & 15;
    const float* src = W_down + (m + 1) * 8192;
    bf16_t* img = (bf16_t*)(wdn_img + m * 16384);
    bf16_t t[8];
#pragma unroll
    for (int j = 0; j < 8; ++j) t[j] = (bf16_t)src[(k8 * 8 + j) * 64 + n];
    const int row = permrow(n);
    *(uint4*)(img + (row << 7) + ((k8 ^ (row & 15)) << 3)) = *(const uint4*)t;
  } else if (blk < 112) {  // Wup [128 rows, K=64] image -> pset slot 0
    const int item = (blk - 108) * 256 + tid;
    const int n = item >> 3, k8 = item & 7;
    bf16_t t[8];
#pragma unroll
    for (int j = 0; j < 8; ++j) t[j] = (bf16_t)W_up[(k8 * 8 + j) * 128 + n];
    const int row = permrow(n);
    *(uint4*)((bf16_t*)pset + (row << 7) + ((k8 ^ (row & 15)) << 3)) = *(const uint4*)t;
  } else {                 // fused W_rbf1@W_rbf2 -> wcb plain [5][128][8]
    const int o = (blk - 112) * 256 + tid;
    if (o < 640) {
      const int b = o >> 7, n = o & 127;
      bf16_t t[8];
#pragma unroll
      for (int r = 0; r < 6; ++r) {
        const float* w1 = W_rbf1 + (b + 1) * 48 + r * 8;
        const float* w2 = W_rbf2 + (b + 1) * 1024 + n;
        float s = 0.f;
#pragma unroll
        for (int c = 0; c < 8; ++c) s += w1[c] * w2[c * 128];
        t[r] = (bf16_t)s;
      }
      t[6] = (bf16_t)0.f; t[7] = (bf16_t)0.f;
      *(uint4*)(wcb + (b * 128 + n) * 8) = *(const uint4*)t;
    }
  }
}

// =====================  K1: branch-fused edge GEMMs (512 thr, 128 rows)  ===========
// 8 waves/CU; raw barriers (no vmcnt drain); ledgered counted vmcnt waits.
__global__ __launch_bounds__(512, 2)
void edge_kernel(const float* __restrict__ x, const float* __restrict__ rbf,
                 const char* __restrict__ wm_img, const char* __restrict__ wdn_img,
                 const bf16_t* __restrict__ wcb,
                 const float* __restrict__ b_ji, const float* __restrict__ b_kj,
                 bf16_t* __restrict__ x_ji_out, bf16_t* __restrict__ down)
{
  __shared__ __align__(16) bf16_t xA[128 * 128];     // 32768 B
  __shared__ __align__(16) bf16_t tmpA[128 * 128];   // 32768 B
  __shared__ __align__(16) bf16_t Wm[2][128 * 128];  // 65536 B
  __shared__ __align__(16) bf16_t Wdn[64 * 128];     // 16384 B
  __shared__ __align__(16) bf16_t rbfS[128 * 8];     // 2048 B
  __shared__ __align__(16) bf16_t wcbS[5 * 128 * 8]; // 10240 B
  __shared__ __align__(16) float biasLDS[6 * 128];   // 3072 B   total 162816

  const int tid = threadIdx.x;
  const int lane = tid & 63, wv = tid >> 6;          // wv 0..7
  const int q = lane >> 4, l16 = lane & 15;
  const int mb = (wv >> 1) * 32, nb = (wv & 1) * 64, nb2 = (wv & 1) * 32;
  const int R = blockIdx.x * 128;

  // ---- VALU staging (all plain loads; drained before DMA ledger starts) ----
  stage_x<32, 512>(xA, x + (size_t)R * 128, tid);
  if (tid < 128) {
    const float* rg = rbf + (size_t)(R + tid) * 6;
    const float2 r01 = *(const float2*)(rg);
    const float2 r23 = *(const float2*)(rg + 2);
    const float2 r45 = *(const float2*)(rg + 4);
    bf16_t t[8] = {(bf16_t)r01.x, (bf16_t)r01.y, (bf16_t)r23.x, (bf16_t)r23.y,
                   (bf16_t)r45.x, (bf16_t)r45.y, (bf16_t)0.f, (bf16_t)0.f};
    *(uint4*)(rbfS + tid * 8) = *(const uint4*)t;
  }
  for (int i = tid; i < 640; i += 512)
    ((uint4*)wcbS)[i] = ((const uint4*)wcb)[i];
  for (int i = tid; i < 768; i += 512) {
    const int b = i >> 7, n = i & 127;
    biasLDS[i] = (b == 0) ? b_ji[n] : b_kj[b * 128 + n];
  }

  VMCNT0();
  dma8<32>(wm_img,          (char*)Wm[0], wv, lane);   // ops 1-4
  dma8<32>(wm_img + 32768,  (char*)Wm[1], wv, lane);   // ops 5-8
  dma8<16>(wdn_img,         (char*)Wdn,   wv, lane);   // ops 9-10
  S_VMCNT(6);        // Wm0 landed (Wm1+Wdn1 in flight)
  BARRIER();

  // ---- br0: x_ji = silu(x @ Wji + b_ji) ----
  {
    f32x4 acc[2][4] = {};
    gemm_tile<4, 4>(xA, Wm[0], mb, nb, l16, q, acc);
    const float* bi = biasLDS;
#pragma unroll
    for (int ti = 0; ti < 2; ++ti)
#pragma unroll
      for (int r = 0; r < 4; ++r) {
        const int row = mb + ti * 16 + q * 4 + r;
#pragma unroll
        for (int gl = 0; gl < 2; ++gl) {
          const int col0 = nb + gl * 32 + 2 * l16;
          const float2 b2 = *(const float2*)&bi[col0];
          *(uint32_t*)&x_ji_out[(size_t)(R + row) * 128 + col0] =
              pack_bf16(silu_f(acc[ti][2 * gl][r] + b2.x),
                        silu_f(acc[ti][2 * gl + 1][r] + b2.y));
        }
      }
  }
  S_VMCNT(18);       // Wm1 landed (16 stores + nothing else after it)
  BARRIER();
  dma8<32>(wm_img + 2 * 32768, (char*)Wm[0], wv, lane);  // Wm2

  // ---- generic branch: ledgered waits (VW1 before B1 ensures Wdn[br];
  //      VW2 before B2 ensures Wm[br+1]); DMA issues only after barriers. ----
#define EDGE_BR(BR, VW1, VW2, NWM, NDN)                                          \
  {                                                                              \
    f32x4 acc[2][4] = {};                                                        \
    gemm_tile<4, 4>(xA, Wm[(BR) & 1], mb, nb, l16, q, acc);                      \
    float wc[2][2][6];                                                           \
    _Pragma("unroll")                                                            \
    for (int gl = 0; gl < 2; ++gl)                                               \
      _Pragma("unroll")                                                          \
      for (int j = 0; j < 2; ++j) {                                              \
        const int col = nb + gl * 32 + 2 * l16 + j;                              \
        bf16x8 w8 = *(const bf16x8*)&wcbS[(((BR) - 1) * 128 + col) * 8];         \
        _Pragma("unroll")                                                        \
        for (int c = 0; c < 6; ++c) wc[gl][j][c] = (float)w8[c];                 \
      }                                                                          \
    const float* bi = biasLDS + (BR) * 128;                                      \
    _Pragma("unroll")                                                            \
    for (int ti = 0; ti < 2; ++ti)                                               \
      _Pragma("unroll")                                                          \
      for (int r = 0; r < 4; ++r) {                                              \
        const int row = mb + ti * 16 + q * 4 + r;                                \
        bf16x8 rv8 = *(const bf16x8*)&rbfS[row * 8];                             \
        float rv[6];                                                             \
        _Pragma("unroll")                                                        \
        for (int c = 0; c < 6; ++c) rv[c] = (float)rv8[c];                       \
        _Pragma("unroll")                                                        \
        for (int gl = 0; gl < 2; ++gl) {                                         \
          const int col0 = nb + gl * 32 + 2 * l16;                               \
          const float2 b2 = *(const float2*)&bi[col0];                           \
          float p0 = 0.f, p1 = 0.f;                                              \
          _Pragma("unroll")                                                      \
          for (int c = 0; c < 6; ++c) {                                          \
            p0 += rv[c] * wc[gl][0][c];                                          \
            p1 += rv[c] * wc[gl][1][c];                                          \
          }                                                                      \
          const float v0 = silu_f(acc[ti][2 * gl][r] + b2.x) * p0;               \
          const float v1 = silu_f(acc[ti][2 * gl + 1][r] + b2.y) * p1;           \
          *(uint32_t*)&tmpA[(row << 7) + ((((col0 >> 3) ^ (row & 15)) << 3) | (col0 & 7))] = \
              pack_bf16(v0, v1);                                                 \
        }                                                                        \
      }                                                                          \
    S_VMCNT(VW1);                                                                \
    BARRIER();                                                                   \
    f32x4 acc2[2][2] = {};                                                       \
    gemm_tile<4, 2>(tmpA, Wdn, mb, nb2, l16, q, acc2);                           \
    _Pragma("unroll")                                                            \
    for (int ti = 0; ti < 2; ++ti)                                               \
      _Pragma("unroll")                                                          \
      for (int r = 0; r < 4; ++r) {                                              \
        const int row = mb + ti * 16 + q * 4 + r;                                \
        const int col0 = nb2 + 2 * l16;                                          \
        *(uint32_t*)&down[((size_t)((BR) - 1) * E_N + R + row) * 64 + col0] =    \
            pack_bf16(silu_f(acc2[ti][0][r]), silu_f(acc2[ti][1][r]));           \
      }                                                                          \
    S_VMCNT(VW2);                                                                \
    BARRIER();                                                                   \
    if ((NDN) >= 0) dma8<16>(wdn_img + (size_t)(NDN) * 16384, (char*)Wdn, wv, lane); \
    if ((NWM) >= 0) dma8<32>(wm_img + (size_t)(NWM) * 32768, (char*)Wm[(BR) & 1], wv, lane); \
  }

  EDGE_BR(1, 20, 8, 3, 1)
  EDGE_BR(2,  4, 8, 4, 2)
  EDGE_BR(3,  4, 8, 5, 3)
  EDGE_BR(4,  4, 8, -1, 4)
  EDGE_BR(5,  0, 63, -1, -1)
#undef EDGE_BR
}

// =====================  K2: triplet c8 projection + CSR bucket build  =====================
__global__ __launch_bounds__(256, 4)
void c8_kernel(const float* __restrict__ sbf, const int* __restrict__ idx_kj,
               const int* __restrict__ idx_ji, const int* __restrict__ bt,
               const float* __restrict__ Wsbf1,
               float* __restrict__ c8g, uint32_t* __restrict__ meta,
               int* __restrict__ cnt, int* __restrict__ list,
               int* __restrict__ ovf)   // ovf[0]=count, pairs (t,ji) from ovf[2]
{
  __shared__ float s_sbf[64 * 44];
  __shared__ float s_W1[2016];   // [6][42][8]
  __shared__ float s_c8[64 * 16];
  __shared__ int s_bs[64];

  const int tid = threadIdx.x;
  const int base = blockIdx.x * 64;

  for (int i = tid; i < 2016; i += 256) s_W1[i] = Wsbf1[i];
  if (tid < 64) {
    const int t = base + tid;
    const int kj = idx_kj[t];
    const int ji = idx_ji[t];
    const int bs = bt[kj] + 1;   // BT_LIST[b] = b-1 for b>=1; bt in [0,5)
    s_bs[tid] = bs;
    meta[t] = (uint32_t)kj | ((uint32_t)bs << 16);
    const int pos = atomicAdd(&cnt[ji], 1);
    if (pos < CAP) {
      list[ji * CAP + pos] = t;
    } else {
      const int o = atomicAdd(&ovf[0], 1);
      if (o < OVF_MAX) { ovf[2 + 2 * o] = t; ovf[2 + 2 * o + 1] = ji; }
    }
  }
  {
    const float2* sg = (const float2*)(sbf + (size_t)base * 42);
    for (int i = tid; i < 64 * 21; i += 256) {
      const int r = i / 21, c2 = i - r * 21;
      const float2 v = sg[i];
      s_sbf[r * 44 + c2 * 2] = v.x;
      s_sbf[r * 44 + c2 * 2 + 1] = v.y;
    }
  }
  __syncthreads();

  { // c8[i][brr*8+c] : brr=0 -> branch 5, brr=1 -> branch bs
    const int i = tid >> 2;
    const int brr = (tid >> 1) & 1;
    const int cg = tid & 1;
    const int b = brr ? s_bs[i] : 5;
    const float* w = &s_W1[b * 336 + cg * 4];
    const float* sb = &s_sbf[i * 44];
    float a0 = 0.f, a1 = 0.f, a2 = 0.f, a3 = 0.f;
#pragma unroll
    for (int s = 0; s < 42; ++s) {
      const float sv = sb[s];
      const float* ws = w + s * 8;
      a0 += sv * ws[0]; a1 += sv * ws[1]; a2 += sv * ws[2]; a3 += sv * ws[3];
    }
    float* dc = &s_c8[i * 16 + brr * 8 + cg * 4];
    dc[0] = a0; dc[1] = a1; dc[2] = a2; dc[3] = a3;
  }
  __syncthreads();

  { // coalesced write-out
    const float4* s4 = (const float4*)s_c8;
    float4* g4 = (float4*)(c8g + (size_t)base * 16);
    g4[tid] = s4[tid];
  }
}

// =====================  K3: per-edge gather (no atomics)  =====================
__global__ __launch_bounds__(256, 8)
void gather_kernel(const int* __restrict__ cnt, const int* __restrict__ list,
                   const uint32_t* __restrict__ meta, const float* __restrict__ c8g,
                   const float* __restrict__ Wsbf2, const bf16_t* __restrict__ down,
                   const float* __restrict__ alpha_p, const int* __restrict__ ovf,
                   float* __restrict__ xkj)
{
  __shared__ float sW2[3072];   // [6][8][64]
  for (int i = threadIdx.x; i < 3072; i += 256) sW2[i] = Wsbf2[i];
  __syncthreads();

  const int e = blockIdx.x * 4 + (threadIdx.x >> 6);
  const int j = threadIdx.x & 63;
  const float alpha = alpha_p[0], oma = 1.f - alpha;
  const float* w5 = &sW2[5 * 512 + j];

  float acc = 0.f;
  int n = cnt[e];
  if (n > CAP) n = CAP;
#pragma unroll 2
  for (int k = 0; k < n; ++k) {
    const int t = __builtin_amdgcn_readfirstlane(list[e * CAP + k]);
    const uint32_t m = __builtin_amdgcn_readfirstlane(meta[t]);
    const int kj = m & 0xffff;
    const int b  = m >> 16;
    const float g5 = (float)down[((size_t)4 * E_N + kj) * 64 + j];
    const float gb = (float)down[((size_t)(b - 1) * E_N + kj) * 64 + j];
    const float* cp = c8g + (size_t)t * 16;
    float d5 = 0.f, db = 0.f;
#pragma unroll
    for (int c = 0; c < 8; ++c) {
      d5 += cp[c]     * w5[c * 64];
      db += cp[8 + c] * sW2[b * 512 + c * 64 + j];
    }
    acc += alpha * g5 * d5 + oma * gb * db;
  }

  const int oc = ovf[0];       // normally 0; full correctness fallback
  for (int k = 0; k < oc; ++k) {
    const int ji = ovf[2 + 2 * k + 1];
    if (ji != e) continue;
    const int t = ovf[2 + 2 * k];
    const uint32_t m = meta[t];
    const int kj = m & 0xffff;
    const int b  = m >> 16;
    const float g5 = (float)down[((size_t)4 * E_N + kj) * 64 + j];
    const float gb = (float)down[((size_t)(b - 1) * E_N + kj) * 64 + j];
    const float* cp = c8g + (size_t)t * 16;
    float d5 = 0.f, db = 0.f;
#pragma unroll
    for (int c = 0; c < 8; ++c) {
      d5 += cp[c]     * w5[c * 64];
      db += cp[8 + c] * sW2[b * 512 + c * 64 + j];
    }
    acc += alpha * g5 * d5 + oma * gb * db;
  }

  xkj[(size_t)e * 64 + j] = acc;
}

// =====================  K4: fused epilogue chain (512 thr, 128 rows)  =====================
__global__ __launch_bounds__(512, 2)
void epi_kernel(const float* __restrict__ x, const bf16_t* __restrict__ x_ji,
                const float* __restrict__ xkj, const char* __restrict__ pset,
                const float* __restrict__ rb1_b, const float* __restrict__ rb2_b,
                const float* __restrict__ lin_b, const float* __restrict__ ra1_b,
                const float* __restrict__ ra2_b,
                float* __restrict__ out)
{
  __shared__ __align__(16) bf16_t bufA[128 * 128];   // 32768 B
  __shared__ __align__(16) bf16_t bufB[128 * 128];   // 32768 B
  __shared__ __align__(16) bf16_t Wset[2][128 * 128];// 65536 B
  __shared__ __align__(16) float biasLDS[5 * 128];   // 2560 B  total 133632

  const int tid = threadIdx.x;
  const int lane = tid & 63, wv = tid >> 6;
  const int q = lane >> 4, l16 = lane & 15;
  const int mb = (wv >> 1) * 32, nb = (wv & 1) * 64;
  const int R = blockIdx.x * 128;

  stage_x<16, 512>(bufA, xkj + (size_t)R * 64, tid);
  for (int i = tid; i < 640; i += 512) {
    const int b = i >> 7, n = i & 127;
    const float* bs = (b == 0) ? rb1_b : (b == 1) ? rb2_b :
                      (b == 2) ? lin_b : (b == 3) ? ra1_b : ra2_b;
    biasLDS[i] = bs[n];
  }
  VMCNT0();
  dma8<32>(pset,          (char*)Wset[0], wv, lane);
  dma8<32>(pset + 32768,  (char*)Wset[1], wv, lane);
  S_VMCNT(4);       // W0 landed, W1 in flight
  BARRIER();

  f32x4 hreg[2][4];
  { // stage 0: h = x_ji + silu(xkj @ W_up)  -> bufB
    f32x4 acc[2][4] = {};
    gemm_tile<2, 4>(bufA, Wset[0], mb, nb, l16, q, acc);
#pragma unroll
    for (int ti = 0; ti < 2; ++ti)
#pragma unroll
      for (int r = 0; r < 4; ++r) {
        const int row = mb + ti * 16 + q * 4 + r;
#pragma unroll
        for (int gl = 0; gl < 2; ++gl) {
          const int col0 = nb + gl * 32 + 2 * l16;
          union { uint32_t u; bf16x2 h; } xj;
          xj.u = *(const uint32_t*)&x_ji[(size_t)(R + row) * 128 + col0];
          const float h0 = (float)xj.h[0] + silu_f(acc[ti][2 * gl][r]);
          const float h1 = (float)xj.h[1] + silu_f(acc[ti][2 * gl + 1][r]);
          hreg[ti][2 * gl][r] = h0;
          hreg[ti][2 * gl + 1][r] = h1;
          *(uint32_t*)&bufB[(row << 7) + ((((col0 >> 3) ^ (row & 15)) << 3) | (col0 & 7))] =
              pack_bf16(h0, h1);
        }
      }
  }
  VMCNT0();          // free: W1 landed during stage 0; xji loads consumed
  BARRIER();
  dma8<32>(pset + 2 * 32768, (char*)Wset[0], wv, lane);

#define EPI_STAGE(K, ASRC, BODY)                                                 \
  {                                                                              \
    const float* biasS = biasLDS + ((K) - 1) * 128;                              \
    f32x4 acc[2][4] = {};                                                        \
    gemm_tile<4, 4>(ASRC, Wset[(K) & 1], mb, nb, l16, q, acc);                   \
    _Pragma("unroll")                                                            \
    for (int ti = 0; ti < 2; ++ti)                                               \
      _Pragma("unroll")                                                          \
      for (int r = 0; r < 4; ++r) {                                              \
        const int row = mb + ti * 16 + q * 4 + r;                                \
        _Pragma("unroll")                                                        \
        for (int gl = 0; gl < 2; ++gl) {                                         \
          const int col0 = nb + gl * 32 + 2 * l16;                               \
          const float2 b2 = *(const float2*)&biasS[col0];                        \
          const float g0 = acc[ti][2 * gl][r] + b2.x;                            \
          const float g1 = acc[ti][2 * gl + 1][r] + b2.y;                        \
          BODY                                                                   \
        }                                                                        \
      }                                                                          \
  }                                                                              \
  VMCNT0();                                                                      \
  BARRIER();                                                                     \
  if ((K) + 2 <= 5)                                                              \
    dma8<32>(pset + (size_t)((K) + 2) * 32768, (char*)Wset[(K) & 1], wv, lane);

  // stage 1: u = silu(h @ rb1 + b) -> bufA
  EPI_STAGE(1, bufB, {
    *(uint32_t*)&bufA[(row << 7) + ((((col0 >> 3) ^ (row & 15)) << 3) | (col0 & 7))] =
        pack_bf16(silu_f(g0), silu_f(g1));
  })

  // stage 2: h += silu(u @ rb2 + b) -> bufB
  EPI_STAGE(2, bufA, {
    const float h0 = hreg[ti][2 * gl][r] + silu_f(g0);
    const float h1 = hreg[ti][2 * gl + 1][r] + silu_f(g1);
    hreg[ti][2 * gl][r] = h0; hreg[ti][2 * gl + 1][r] = h1;
    *(uint32_t*)&bufB[(row << 7) + ((((col0 >> 3) ^ (row & 15)) << 3) | (col0 & 7))] =
        pack_bf16(h0, h1);
  })

  // stage 3: h = silu(h @ W_lin + b) + x -> bufA
  EPI_STAGE(3, bufB, {
    const float2 xv = *(const float2*)&x[(size_t)(R + row) * 128 + col0];
    const float h0 = silu_f(g0) + xv.x;
    const float h1 = silu_f(g1) + xv.y;
    hreg[ti][2 * gl][r] = h0; hreg[ti][2 * gl + 1][r] = h1;
    *(uint32_t*)&bufA[(row << 7) + ((((col0 >> 3) ^ (row & 15)) << 3) | (col0 & 7))] =
        pack_bf16(h0, h1);
  })

  // stage 4: u = silu(h @ ra1 + b) -> bufB
  EPI_STAGE(4, bufA, {
    *(uint32_t*)&bufB[(row << 7) + ((((col0 >> 3) ^ (row & 15)) << 3) | (col0 & 7))] =
        pack_bf16(silu_f(g0), silu_f(g1));
  })

  // stage 5: out = h + silu(u @ ra2 + b)
  EPI_STAGE(5, bufB, {
    float2 o;
    o.x = hreg[ti][2 * gl][r] + silu_f(g0);
    o.y = hreg[ti][2 * gl + 1][r] + silu_f(g1);
    *(float2*)&out[(size_t)(R + row) * 128 + col0] = o;
  })
#undef EPI_STAGE
}

extern "C" void kernel_launch(void* const* d_in, const int* in_sizes, int n_in,
                              void* d_out, int out_size, void* d_ws, size_t ws_size,
                              hipStream_t stream)
{
  (void)in_sizes; (void)n_in; (void)out_size; (void)ws_size;
  const float* x      = (const float*)d_in[0];
  const float* rbf    = (const float*)d_in[1];
  const float* sbf    = (const float*)d_in[2];
  const int*   idx_kj = (const int*)d_in[3];
  const int*   idx_ji = (const int*)d_in[4];
  const int*   bt     = (const int*)d_in[5];
  const float* alpha  = (const float*)d_in[7];
  const float* W_kj   = (const float*)d_in[8];
  const float* b_kj   = (const float*)d_in[9];
  const float* W_rbf1 = (const float*)d_in[10];
  const float* W_rbf2 = (const float*)d_in[11];
  const float* W_sbf1 = (const float*)d_in[12];
  const float* W_sbf2 = (const float*)d_in[13];
  const float* W_down = (const float*)d_in[14];
  const float* W_ji   = (const float*)d_in[15];
  const float* b_ji   = (const float*)d_in[16];
  const float* W_up   = (const float*)d_in[17];
  const float* rb1_w  = (const float*)d_in[18];
  const float* rb1_b  = (const float*)d_in[19];
  const float* rb2_w  = (const float*)d_in[20];
  const float* rb2_b  = (const float*)d_in[21];
  const float* W_lin  = (const float*)d_in[22];
  const float* b_lin  = (const float*)d_in[23];
  const float* ra1_w  = (const float*)d_in[24];
  const float* ra1_b  = (const float*)d_in[25];
  const float* ra2_w  = (const float*)d_in[26];
  const float* ra2_b  = (const float*)d_in[27];

  char* ws = (char*)d_ws;
  bf16_t* down   = (bf16_t*)(ws);                 // 5*E*64*2  = 41,943,040
  bf16_t* x_ji   = (bf16_t*)(ws + 41943040);      // E*128*2   = 16,777,216
  float*  xkj    = (float*) (ws + 58720256);      // E*64*4    = 16,777,216
  char*   wm_img = ws + 75497472;                 // 6*32768   =    196,608
  char*   wdn_img= ws + 75694080;                 // 5*16384   =     81,920
  char*   pset   = ws + 75776000;                 // 6*32768   =    196,608
  bf16_t* wcb    = (bf16_t*)(ws + 75972608);      // 5*128*8*2 =     10,240
  float*    c8g  = (float*)   (ws + 75982848);    // T*16*4    = 16,777,216
  uint32_t* meta = (uint32_t*)(ws + 92760064);    // T*4       =  1,048,576
  int*      list = (int*)     (ws + 93808640);    // E*CAP*4   =  4,194,304
  int*      cnt  = (int*)     (ws + 98002944);    // E*4       =    262,144
  int*      ovf  = (int*)     (ws + 98265088);    // 8 + 2*T*4 =  2,097,160

  hipMemsetAsync(cnt, 0, 262144 + 8, stream);     // cnt + ovf[0..1]
  prep_kernel<<<115, 256, 0, stream>>>(W_ji, W_kj, W_down, W_up, rb1_w, rb2_w,
                                       W_lin, ra1_w, ra2_w, W_rbf1, W_rbf2,
                                       wm_img, wdn_img, pset, wcb);
  edge_kernel<<<E_N / 128, 512, 0, stream>>>(x, rbf, wm_img, wdn_img, wcb,
                                             b_ji, b_kj, x_ji, down);
  c8_kernel<<<T_N / 64, 256, 0, stream>>>(sbf, idx_kj, idx_ji, bt, W_sbf1,
                                          c8g, meta, cnt, list, ovf);
  gather_kernel<<<E_N / 4 / 64, 256, 0, stream>>>(cnt, list, meta, c8g, W_sbf2,
                                                  down, alpha, ovf, xkj);
  epi_kernel<<<E_N / 128, 512, 0, stream>>>(x, x_ji, xkj, pset,
                                            rb1_b, rb2_b, b_lin, ra1_b, ra2_b,
                                            (float*)d_out);
}

// Round 4
// 388.648 us; speedup vs baseline: 1.0752x; 1.0752x over previous
//
#include <hip/hip_runtime.h>
#include <hip/hip_bf16.h>
#include <stdint.h>

typedef __bf16 bf16_t;
typedef bf16_t bf16x8 __attribute__((ext_vector_type(8)));
typedef bf16_t bf16x2 __attribute__((ext_vector_type(2)));
typedef float f32x4 __attribute__((ext_vector_type(4)));

#define E_N 65536
#define T_N 262144
#define CAP 16          // bucket capacity per edge (avg occupancy 4)
#define OVF_MAX T_N     // overflow list can hold every triplet -> always correct

__device__ __forceinline__ float silu_f(float v) {
  return v / (1.0f + __expf(-v));
}

// B-row permutation: LDS row r = tj*16+i holds real output column
// 32*(tj>>1) + 2*i + (tj&1), so each lane's acc[2g],acc[2g+1] are 2
// consecutive real columns -> bf16x2 stores everywhere.
__device__ __forceinline__ int permrow(int n) {
  return (n & ~31) | ((n & 1) << 4) | ((n & 30) >> 1);
}

__device__ __forceinline__ uint32_t pack_bf16(float a, float b) {
  union { bf16x2 h; uint32_t u; } u;
  u.h[0] = (bf16_t)a; u.h[1] = (bf16_t)b;
  return u.u;
}

// ---- MFMA tile GEMM on swizzled stride-128 LDS tiles ----
// element (row,k) stored at row*128 + (((k>>3) ^ (row&15))<<3) + (k&7)
template<int KI, int NTJ>
__device__ __forceinline__ void gemm_tile(const bf16_t* A, const bf16_t* B,
                                          int mb, int nb, int l16, int q,
                                          f32x4 (&acc)[2][NTJ]) {
#pragma unroll
  for (int kt = 0; kt < KI; ++kt) {
    const int sw = ((kt * 4 + q) ^ l16) << 3;
    bf16x8 a0 = *(const bf16x8*)(A + ((mb + l16) << 7) + sw);
    bf16x8 a1 = *(const bf16x8*)(A + ((mb + 16 + l16) << 7) + sw);
#pragma unroll
    for (int tj = 0; tj < NTJ; ++tj) {
      bf16x8 b = *(const bf16x8*)(B + ((nb + tj * 16 + l16) << 7) + sw);
      acc[0][tj] = __builtin_amdgcn_mfma_f32_16x16x32_bf16(a0, b, acc[0][tj], 0, 0, 0);
      acc[1][tj] = __builtin_amdgcn_mfma_f32_16x16x32_bf16(a1, b, acc[1][tj], 0, 0, 0);
    }
  }
}

// Load transposed bf16 weight [N][K] global -> perm'd+swizzled LDS.
template<int ROWS, int K8>
__device__ __forceinline__ void load_wT(bf16_t* dst, const bf16_t* src, int tid) {
  const uint4* s = (const uint4*)src;
#pragma unroll
  for (int i = tid; i < ROWS * K8; i += 256) {
    const int n = i / K8, k8 = i % K8;
    const int row = permrow(n);
    *(uint4*)(dst + (row << 7) + ((k8 ^ (row & 15)) << 3)) = s[i];
  }
}

// Stage fp32 [64][K] tile -> swizzled bf16 LDS. C4 = K/4.
template<int C4>
__device__ __forceinline__ void stage_x(bf16_t* dst, const float* src, int tid) {
  const float4* g = (const float4*)src;
#pragma unroll
  for (int i = tid; i < 64 * C4; i += 256) {
    const int row = i / C4, c4 = i % C4;
    float4 v = g[i];
    bf16_t t[4] = {(bf16_t)v.x, (bf16_t)v.y, (bf16_t)v.z, (bf16_t)v.w};
    *(uint2*)(dst + (row << 7) + ((((c4 >> 1) ^ (row & 15)) << 3) | ((c4 & 1) << 2))) =
        *(const uint2*)t;
  }
}

// =====================  K0: weight preprocessing  =====================
// Transpose all fp32 weights to bf16 [N][K]; fuse W_rbf1@W_rbf2 -> wcb[b][n][8].
__global__ void prep_kernel(
    const float* __restrict__ W_ji, const float* __restrict__ W_kj,
    const float* __restrict__ W_down, const float* __restrict__ W_up,
    const float* __restrict__ rb1, const float* __restrict__ rb2,
    const float* __restrict__ W_lin, const float* __restrict__ ra1,
    const float* __restrict__ ra2, const float* __restrict__ W_rbf1,
    const float* __restrict__ W_rbf2,
    bf16_t* __restrict__ wjiT, bf16_t* __restrict__ wkjT,
    bf16_t* __restrict__ wdownT, bf16_t* __restrict__ wupT,
    bf16_t* __restrict__ rb1T, bf16_t* __restrict__ rb2T,
    bf16_t* __restrict__ linT, bf16_t* __restrict__ ra1T,
    bf16_t* __restrict__ ra2T, bf16_t* __restrict__ wcb)
{
  const int tid = threadIdx.x;
  if (blockIdx.x >= 112) {
    const int o = (blockIdx.x - 112) * 256 + tid;
    if (o < 640) {
      const int b = o >> 7, n = o & 127;
      bf16_t t[8];
#pragma unroll
      for (int r = 0; r < 6; ++r) {
        const float* w1 = W_rbf1 + (b + 1) * 48 + r * 8;
        const float* w2 = W_rbf2 + (b + 1) * 1024 + n;
        float s = 0.f;
#pragma unroll
        for (int c = 0; c < 8; ++c) s += w1[c] * w2[c * 128];
        t[r] = (bf16_t)s;
      }
      t[6] = (bf16_t)0.f; t[7] = (bf16_t)0.f;
      *(uint4*)(wcb + (b * 128 + n) * 8) = *(const uint4*)t;
    }
    return;
  }
  const int c = blockIdx.x * 256 + tid;
  const float* src; bf16_t* dst; int n, k8, N, K;
  if (c < 22528) {
    const int m = c >> 11, w = c & 2047;
    n = w >> 4; k8 = w & 15; N = 128; K = 128;
    if (m == 0)      { src = W_ji;  dst = wjiT; }
    else if (m <= 5) { src = W_kj + m * 16384; dst = wkjT + (m - 1) * 16384; }
    else if (m == 6) { src = rb1;   dst = rb1T; }
    else if (m == 7) { src = rb2;   dst = rb2T; }
    else if (m == 8) { src = W_lin; dst = linT; }
    else if (m == 9) { src = ra1;   dst = ra1T; }
    else             { src = ra2;   dst = ra2T; }
  } else if (c < 27648) {
    const int m = (c - 22528) >> 10, w = (c - 22528) & 1023;
    n = w >> 4; k8 = w & 15; N = 64; K = 128;
    src = W_down + (m + 1) * 8192; dst = wdownT + m * 8192;
  } else {
    const int w = c - 27648;
    n = w >> 3; k8 = w & 7; N = 128; K = 64;
    src = W_up; dst = wupT;
  }
  bf16_t t[8];
#pragma unroll
  for (int j = 0; j < 8; ++j) t[j] = (bf16_t)src[(k8 * 8 + j) * N + n];
  *(uint4*)(dst + n * K + k8 * 8) = *(const uint4*)t;
}

// =====================  K1: fused edge GEMMs + triplet c8 (one grid)  ============
// bid%5 in {0,1,2} -> edge block (6144 total), bid%5 in {3,4} -> c8 block (4096).
// Edge and c8 have no data dependency; co-residency lets c8's VALU/mem work
// fill edge's stall gaps (MFMA and VALU pipes co-schedule).
__global__ __launch_bounds__(256, 2)
void edge_c8_kernel(const float* __restrict__ x, const float* __restrict__ rbf,
                    const float* __restrict__ b_kj, const float* __restrict__ b_ji,
                    const bf16_t* __restrict__ wjiT, const bf16_t* __restrict__ wkjT,
                    const bf16_t* __restrict__ wdownT, const bf16_t* __restrict__ wcb,
                    bf16_t* __restrict__ x_ji_out, bf16_t* __restrict__ down,
                    const float* __restrict__ sbf, const int* __restrict__ idx_kj,
                    const int* __restrict__ idx_ji, const int* __restrict__ bt,
                    const float* __restrict__ Wsbf1,
                    float* __restrict__ c8g, uint32_t* __restrict__ meta,
                    int* __restrict__ cnt, int* __restrict__ list,
                    int* __restrict__ ovf)
{
  __shared__ union {
    struct {                      // edge path: 66048 B
      bf16_t xA[64 * 128];
      bf16_t Wb[128 * 128];
      bf16_t tmpA[64 * 128];      // also aliases rbfA (64*40) + WcB (128*40)
      float biasS[128];
    } e;
    struct {                      // c8 path: 23680 B
      float s_sbf[64 * 44];
      float s_W1[2016];           // [6][42][8]
      float s_c8[64 * 16];
      int s_bs[64];
    } c;
  } S;

  const int tid = threadIdx.x;
  const int bid = blockIdx.x;
  const int g = bid / 5, m5 = bid % 5;

  if (m5 < 3) {
    // ==================== edge path ====================
    const int eb = g * 3 + m5;       // 0..6143
    const int br = eb % 6;           // 0 = x_ji, 1..5 = branch pipelines
    const int R = (eb / 6) * 64;     // row tile; 6 consecutive eb share it (L2)

    bf16_t* const rbfA = S.e.tmpA;
    bf16_t* const WcB  = S.e.tmpA + 64 * 40;

    const int lane = tid & 63, wv = tid >> 6;
    const int q = lane >> 4, l16 = lane & 15;
    const int mb = (wv >> 1) * 32, nb = (wv & 1) * 64;

    stage_x<32>(S.e.xA, x + (size_t)R * 128, tid);
    if (br == 0) {
      load_wT<128, 16>(S.e.Wb, wjiT, tid);
      if (tid < 128) S.e.biasS[tid] = b_ji[tid];
    } else {
      load_wT<128, 16>(S.e.Wb, wkjT + (br - 1) * 16384, tid);
      if (tid < 128) S.e.biasS[tid] = b_kj[br * 128 + tid];
      const uint4 z = {0, 0, 0, 0};
      if (tid < 64) {
        const float* rg = rbf + (size_t)(R + tid) * 6;
        bf16_t t[8] = {(bf16_t)rg[0], (bf16_t)rg[1], (bf16_t)rg[2],
                       (bf16_t)rg[3], (bf16_t)rg[4], (bf16_t)rg[5],
                       (bf16_t)0.f, (bf16_t)0.f};
        *(uint4*)(rbfA + tid * 40)      = *(const uint4*)t;
        *(uint4*)(rbfA + tid * 40 + 8)  = z;
        *(uint4*)(rbfA + tid * 40 + 16) = z;
        *(uint4*)(rbfA + tid * 40 + 24) = z;
      } else if (tid >= 128) {
        const int n = tid - 128;   // 0..127, perm'd row order
        const int row = permrow(n);
        uint4 w = ((const uint4*)(wcb + (size_t)(br - 1) * 1024))[n];
        *(uint4*)(WcB + row * 40)      = w;
        *(uint4*)(WcB + row * 40 + 8)  = z;
        *(uint4*)(WcB + row * 40 + 16) = z;
        *(uint4*)(WcB + row * 40 + 24) = z;
      }
    }
    __syncthreads();

    f32x4 acc[2][4] = {};
    gemm_tile<4, 4>(S.e.xA, S.e.Wb, mb, nb, l16, q, acc);

    if (br == 0) {
#pragma unroll
      for (int ti = 0; ti < 2; ++ti)
#pragma unroll
        for (int r = 0; r < 4; ++r) {
          const int row = mb + ti * 16 + q * 4 + r;
#pragma unroll
          for (int gl = 0; gl < 2; ++gl) {
            const int col0 = nb + gl * 32 + 2 * l16;
            const float2 b2 = *(const float2*)&S.e.biasS[col0];
            *(uint32_t*)&x_ji_out[(size_t)(R + row) * 128 + col0] =
                pack_bf16(silu_f(acc[ti][2 * gl][r] + b2.x),
                          silu_f(acc[ti][2 * gl + 1][r] + b2.y));
          }
        }
      return;
    }

    // rbf_p = rbf @ Wc via one-K-step MFMA (real K=6, padded to 32)
    f32x4 accr[2][4] = {};
    {
      bf16x8 a0 = *(const bf16x8*)(rbfA + (mb + l16) * 40 + q * 8);
      bf16x8 a1 = *(const bf16x8*)(rbfA + (mb + 16 + l16) * 40 + q * 8);
#pragma unroll
      for (int tj = 0; tj < 4; ++tj) {
        bf16x8 b = *(const bf16x8*)(WcB + (nb + tj * 16 + l16) * 40 + q * 8);
        accr[0][tj] = __builtin_amdgcn_mfma_f32_16x16x32_bf16(a0, b, accr[0][tj], 0, 0, 0);
        accr[1][tj] = __builtin_amdgcn_mfma_f32_16x16x32_bf16(a1, b, accr[1][tj], 0, 0, 0);
      }
    }
    __syncthreads();   // all reads of rbfA/WcB done before tmpA overwrites them

    // tmp = silu(x@Wkj + b) * rbf_p  -> swizzled A-layout in tmpA
#pragma unroll
    for (int ti = 0; ti < 2; ++ti)
#pragma unroll
      for (int r = 0; r < 4; ++r) {
        const int row = mb + ti * 16 + q * 4 + r;
#pragma unroll
        for (int gl = 0; gl < 2; ++gl) {
          const int col0 = nb + gl * 32 + 2 * l16;
          const float2 b2 = *(const float2*)&S.e.biasS[col0];
          const float v0 = silu_f(acc[ti][2 * gl][r] + b2.x) * accr[ti][2 * gl][r];
          const float v1 = silu_f(acc[ti][2 * gl + 1][r] + b2.y) * accr[ti][2 * gl + 1][r];
          *(uint32_t*)&S.e.tmpA[(row << 7) + ((((col0 >> 3) ^ (row & 15)) << 3) | (col0 & 7))] =
              pack_bf16(v0, v1);
        }
      }
    __syncthreads();
    load_wT<64, 16>(S.e.xA, wdownT + (br - 1) * 8192, tid);   // Wdown into xA space
    __syncthreads();

    const int nb2 = (wv & 1) * 32;
    f32x4 acc2[2][2] = {};
    gemm_tile<4, 2>(S.e.tmpA, S.e.xA, mb, nb2, l16, q, acc2);
#pragma unroll
    for (int ti = 0; ti < 2; ++ti)
#pragma unroll
      for (int r = 0; r < 4; ++r) {
        const int row = mb + ti * 16 + q * 4 + r;
        const int col0 = nb2 + 2 * l16;
        *(uint32_t*)&down[((size_t)(br - 1) * E_N + R + row) * 64 + col0] =
            pack_bf16(silu_f(acc2[ti][0][r]), silu_f(acc2[ti][1][r]));
      }
    return;
  }

  // ==================== c8 path ====================
  {
    const int ct = g * 2 + (m5 - 3);   // 0..4095
    const int base = ct * 64;

    for (int i = tid; i < 2016; i += 256) S.c.s_W1[i] = Wsbf1[i];
    if (tid < 64) {
      const int t = base + tid;
      const int kj = idx_kj[t];
      const int ji = idx_ji[t];
      const int bs = bt[kj] + 1;   // BT_LIST[b] = b-1 for b>=1; bt in [0,5)
      S.c.s_bs[tid] = bs;
      meta[t] = (uint32_t)kj | ((uint32_t)bs << 16);
      const int pos = atomicAdd(&cnt[ji], 1);
      if (pos < CAP) {
        list[ji * CAP + pos] = t;
      } else {
        const int o = atomicAdd(&ovf[0], 1);
        if (o < OVF_MAX) { ovf[2 + 2 * o] = t; ovf[2 + 2 * o + 1] = ji; }
      }
    }
    {
      const float2* sg = (const float2*)(sbf + (size_t)base * 42);
      for (int i = tid; i < 64 * 21; i += 256) {
        const int r = i / 21, c2 = i - r * 21;
        const float2 v = sg[i];
        S.c.s_sbf[r * 44 + c2 * 2] = v.x;
        S.c.s_sbf[r * 44 + c2 * 2 + 1] = v.y;
      }
    }
    __syncthreads();

    { // c8[i][brr*8+c] : brr=0 -> branch 5, brr=1 -> branch bs
      const int i = tid >> 2;
      const int brr = (tid >> 1) & 1;
      const int cg = tid & 1;
      const int b = brr ? S.c.s_bs[i] : 5;
      const float* w = &S.c.s_W1[b * 336 + cg * 4];
      const float* sb = &S.c.s_sbf[i * 44];
      float a0 = 0.f, a1 = 0.f, a2 = 0.f, a3 = 0.f;
#pragma unroll
      for (int s = 0; s < 42; ++s) {
        const float sv = sb[s];
        const float* ws = w + s * 8;
        a0 += sv * ws[0]; a1 += sv * ws[1]; a2 += sv * ws[2]; a3 += sv * ws[3];
      }
      float* dc = &S.c.s_c8[i * 16 + brr * 8 + cg * 4];
      dc[0] = a0; dc[1] = a1; dc[2] = a2; dc[3] = a3;
    }
    __syncthreads();

    { // coalesced write-out: 256 threads x float4 = 64 triplets x 16 floats
      const float4* s4 = (const float4*)S.c.s_c8;
      float4* g4 = (float4*)(c8g + (size_t)base * 16);
      g4[tid] = s4[tid];
    }
  }
}

// =====================  K3: per-edge gather (no atomics)  =====================
__global__ __launch_bounds__(256, 8)
void gather_kernel(const int* __restrict__ cnt, const int* __restrict__ list,
                   const uint32_t* __restrict__ meta, const float* __restrict__ c8g,
                   const float* __restrict__ Wsbf2, const bf16_t* __restrict__ down,
                   const float* __restrict__ alpha_p, const int* __restrict__ ovf,
                   float* __restrict__ xkj)
{
  __shared__ float sW2[3072];   // [6][8][64]
  for (int i = threadIdx.x; i < 3072; i += 256) sW2[i] = Wsbf2[i];
  __syncthreads();

  const int e = blockIdx.x * 4 + (threadIdx.x >> 6);
  const int j = threadIdx.x & 63;
  const float alpha = alpha_p[0], oma = 1.f - alpha;
  const float* w5 = &sW2[5 * 512 + j];

  float acc = 0.f;
  int n = cnt[e];
  if (n > CAP) n = CAP;
#pragma unroll 2
  for (int k = 0; k < n; ++k) {
    const int t = __builtin_amdgcn_readfirstlane(list[e * CAP + k]);
    const uint32_t m = __builtin_amdgcn_readfirstlane(meta[t]);
    const int kj = m & 0xffff;
    const int b  = m >> 16;
    const float g5 = (float)down[((size_t)4 * E_N + kj) * 64 + j];
    const float gb = (float)down[((size_t)(b - 1) * E_N + kj) * 64 + j];
    const float* cp = c8g + (size_t)t * 16;
    float d5 = 0.f, db = 0.f;
#pragma unroll
    for (int c = 0; c < 8; ++c) {
      d5 += cp[c]     * w5[c * 64];
      db += cp[8 + c] * sW2[b * 512 + c * 64 + j];
    }
    acc += alpha * g5 * d5 + oma * gb * db;
  }

  const int oc = ovf[0];       // normally 0; full correctness fallback
  for (int k = 0; k < oc; ++k) {
    const int ji = ovf[2 + 2 * k + 1];
    if (ji != e) continue;
    const int t = ovf[2 + 2 * k];
    const uint32_t m = meta[t];
    const int kj = m & 0xffff;
    const int b  = m >> 16;
    const float g5 = (float)down[((size_t)4 * E_N + kj) * 64 + j];
    const float gb = (float)down[((size_t)(b - 1) * E_N + kj) * 64 + j];
    const float* cp = c8g + (size_t)t * 16;
    float d5 = 0.f, db = 0.f;
#pragma unroll
    for (int c = 0; c < 8; ++c) {
      d5 += cp[c]     * w5[c * 64];
      db += cp[8 + c] * sW2[b * 512 + c * 64 + j];
    }
    acc += alpha * g5 * d5 + oma * gb * db;
  }

  xkj[(size_t)e * 64 + j] = acc;
}

// =====================  K4: fused epilogue chain  =====================
__global__ __launch_bounds__(256, 2)
void epi_kernel(const float* __restrict__ x, const bf16_t* __restrict__ x_ji,
                const float* __restrict__ xkj,
                const bf16_t* __restrict__ wupT,
                const bf16_t* __restrict__ rb1T, const float* __restrict__ rb1_b,
                const bf16_t* __restrict__ rb2T, const float* __restrict__ rb2_b,
                const bf16_t* __restrict__ linT, const float* __restrict__ lin_b,
                const bf16_t* __restrict__ ra1T, const float* __restrict__ ra1_b,
                const bf16_t* __restrict__ ra2T, const float* __restrict__ ra2_b,
                float* __restrict__ out)
{
  __shared__ bf16_t bufA[64 * 128];
  __shared__ bf16_t bufB[64 * 128];
  __shared__ bf16_t Wb[128 * 128];
  __shared__ float biasS[128];

  const int tid = threadIdx.x;
  const int lane = tid & 63, wv = tid >> 6;
  const int q = lane >> 4, l16 = lane & 15;
  const int mb = (wv >> 1) * 32, nb = (wv & 1) * 64;
  const int R = blockIdx.x * 64;

  stage_x<16>(bufA, xkj + (size_t)R * 64, tid);
  load_wT<128, 8>(Wb, wupT, tid);
  __syncthreads();

  f32x4 hreg[2][4];
  { // h = x_ji + silu(xkj @ W_up)  -> bufB
    f32x4 acc[2][4] = {};
    gemm_tile<2, 4>(bufA, Wb, mb, nb, l16, q, acc);
#pragma unroll
    for (int ti = 0; ti < 2; ++ti)
#pragma unroll
      for (int r = 0; r < 4; ++r) {
        const int row = mb + ti * 16 + q * 4 + r;
#pragma unroll
        for (int gl = 0; gl < 2; ++gl) {
          const int col0 = nb + gl * 32 + 2 * l16;
          union { uint32_t u; bf16x2 h; } xj;
          xj.u = *(const uint32_t*)&x_ji[(size_t)(R + row) * 128 + col0];
          const float h0 = (float)xj.h[0] + silu_f(acc[ti][2 * gl][r]);
          const float h1 = (float)xj.h[1] + silu_f(acc[ti][2 * gl + 1][r]);
          hreg[ti][2 * gl][r] = h0;
          hreg[ti][2 * gl + 1][r] = h1;
          *(uint32_t*)&bufB[(row << 7) + ((((col0 >> 3) ^ (row & 15)) << 3) | (col0 & 7))] =
              pack_bf16(h0, h1);
        }
      }
  }

#define EPI_STAGE(ASRC, WSRC, BIAS, BODY)                                        \
  __syncthreads();                                                               \
  load_wT<128, 16>(Wb, WSRC, tid);                                               \
  if (tid < 128) biasS[tid] = BIAS[tid];                                         \
  __syncthreads();                                                               \
  {                                                                              \
    f32x4 acc[2][4] = {};                                                        \
    gemm_tile<4, 4>(ASRC, Wb, mb, nb, l16, q, acc);                              \
    _Pragma("unroll")                                                            \
    for (int ti = 0; ti < 2; ++ti)                                               \
      _Pragma("unroll")                                                          \
      for (int r = 0; r < 4; ++r) {                                              \
        const int row = mb + ti * 16 + q * 4 + r;                                \
        _Pragma("unroll")                                                        \
        for (int gl = 0; gl < 2; ++gl) {                                         \
          const int col0 = nb + gl * 32 + 2 * l16;                               \
          const float2 b2 = *(const float2*)&biasS[col0];                        \
          const float g0 = acc[ti][2 * gl][r] + b2.x;                            \
          const float g1 = acc[ti][2 * gl + 1][r] + b2.y;                        \
          BODY                                                                   \
        }                                                                        \
      }                                                                          \
  }

  // stage 1: u = silu(h @ rb1 + b) -> bufA
  EPI_STAGE(bufB, rb1T, rb1_b, {
    *(uint32_t*)&bufA[(row << 7) + ((((col0 >> 3) ^ (row & 15)) << 3) | (col0 & 7))] =
        pack_bf16(silu_f(g0), silu_f(g1));
  })

  // stage 2: h += silu(u @ rb2 + b) -> bufB
  EPI_STAGE(bufA, rb2T, rb2_b, {
    const float h0 = hreg[ti][2 * gl][r] + silu_f(g0);
    const float h1 = hreg[ti][2 * gl + 1][r] + silu_f(g1);
    hreg[ti][2 * gl][r] = h0; hreg[ti][2 * gl + 1][r] = h1;
    *(uint32_t*)&bufB[(row << 7) + ((((col0 >> 3) ^ (row & 15)) << 3) | (col0 & 7))] =
        pack_bf16(h0, h1);
  })

  // stage 3: h = silu(h @ W_lin + b) + x -> bufA
  EPI_STAGE(bufB, linT, lin_b, {
    const float2 xv = *(const float2*)&x[(size_t)(R + row) * 128 + col0];
    const float h0 = silu_f(g0) + xv.x;
    const float h1 = silu_f(g1) + xv.y;
    hreg[ti][2 * gl][r] = h0; hreg[ti][2 * gl + 1][r] = h1;
    *(uint32_t*)&bufA[(row << 7) + ((((col0 >> 3) ^ (row & 15)) << 3) | (col0 & 7))] =
        pack_bf16(h0, h1);
  })

  // stage 4: u = silu(h @ ra1 + b) -> bufB
  EPI_STAGE(bufA, ra1T, ra1_b, {
    *(uint32_t*)&bufB[(row << 7) + ((((col0 >> 3) ^ (row & 15)) << 3) | (col0 & 7))] =
        pack_bf16(silu_f(g0), silu_f(g1));
  })

  // stage 5: out = h + silu(u @ ra2 + b)
  EPI_STAGE(bufB, ra2T, ra2_b, {
    float2 o;
    o.x = hreg[ti][2 * gl][r] + silu_f(g0);
    o.y = hreg[ti][2 * gl + 1][r] + silu_f(g1);
    *(float2*)&out[(size_t)(R + row) * 128 + col0] = o;
  })
#undef EPI_STAGE
}

extern "C" void kernel_launch(void* const* d_in, const int* in_sizes, int n_in,
                              void* d_out, int out_size, void* d_ws, size_t ws_size,
                              hipStream_t stream)
{
  (void)in_sizes; (void)n_in; (void)out_size; (void)ws_size;
  const float* x      = (const float*)d_in[0];
  const float* rbf    = (const float*)d_in[1];
  const float* sbf    = (const float*)d_in[2];
  const int*   idx_kj = (const int*)d_in[3];
  const int*   idx_ji = (const int*)d_in[4];
  const int*   bt     = (const int*)d_in[5];
  const float* alpha  = (const float*)d_in[7];
  const float* W_kj   = (const float*)d_in[8];
  const float* b_kj   = (const float*)d_in[9];
  const float* W_rbf1 = (const float*)d_in[10];
  const float* W_rbf2 = (const float*)d_in[11];
  const float* W_sbf1 = (const float*)d_in[12];
  const float* W_sbf2 = (const float*)d_in[13];
  const float* W_down = (const float*)d_in[14];
  const float* W_ji   = (const float*)d_in[15];
  const float* b_ji   = (const float*)d_in[16];
  const float* W_up   = (const float*)d_in[17];
  const float* rb1_w  = (const float*)d_in[18];
  const float* rb1_b  = (const float*)d_in[19];
  const float* rb2_w  = (const float*)d_in[20];
  const float* rb2_b  = (const float*)d_in[21];
  const float* W_lin  = (const float*)d_in[22];
  const float* b_lin  = (const float*)d_in[23];
  const float* ra1_w  = (const float*)d_in[24];
  const float* ra1_b  = (const float*)d_in[25];
  const float* ra2_w  = (const float*)d_in[26];
  const float* ra2_b  = (const float*)d_in[27];

  char* ws = (char*)d_ws;
  bf16_t* down   = (bf16_t*)(ws);                 // 5*E*64*2  = 41,943,040
  bf16_t* x_ji   = (bf16_t*)(ws + 41943040);      // E*128*2   = 16,777,216
  float*  xkj    = (float*) (ws + 58720256);      // E*64*4    = 16,777,216
  char* wbase    = ws + 75497472;
  bf16_t* wjiT   = (bf16_t*)(wbase + 0);
  bf16_t* wkjT   = (bf16_t*)(wbase + 32768);
  bf16_t* wdownT = (bf16_t*)(wbase + 196608);
  bf16_t* wupT   = (bf16_t*)(wbase + 278528);
  bf16_t* rb1T   = (bf16_t*)(wbase + 294912);
  bf16_t* rb2T   = (bf16_t*)(wbase + 327680);
  bf16_t* linT   = (bf16_t*)(wbase + 360448);
  bf16_t* ra1T   = (bf16_t*)(wbase + 393216);
  bf16_t* ra2T   = (bf16_t*)(wbase + 425984);
  bf16_t* wcb    = (bf16_t*)(wbase + 458752);     // 5*128*8*2 = 10,240
  float*    c8g  = (float*)   (ws + 75966464);    // T*16*4    = 16,777,216
  uint32_t* meta = (uint32_t*)(ws + 92743680);    // T*4       =  1,048,576
  int*      list = (int*)     (ws + 93792256);    // E*CAP*4   =  4,194,304
  int*      cnt  = (int*)     (ws + 97986560);    // E*4       =    262,144
  int*      ovf  = (int*)     (ws + 98248704);    // 8 + 2*T*4 =  2,097,160

  hipMemsetAsync(cnt, 0, 262144 + 8, stream);     // cnt + ovf[0..1]
  prep_kernel<<<115, 256, 0, stream>>>(W_ji, W_kj, W_down, W_up, rb1_w, rb2_w,
                                       W_lin, ra1_w, ra2_w, W_rbf1, W_rbf2,
                                       wjiT, wkjT, wdownT, wupT, rb1T, rb2T,
                                       linT, ra1T, ra2T, wcb);
  // fused edge (6144 blocks) + c8 (4096 blocks): 10240 blocks, 2/5 are c8,
  // interleaved through dispatch so MFMA and VALU/mem blocks co-reside.
  edge_c8_kernel<<<10240, 256, 0, stream>>>(x, rbf, b_kj, b_ji, wjiT, wkjT,
                                            wdownT, wcb, x_ji, down,
                                            sbf, idx_kj, idx_ji, bt, W_sbf1,
                                            c8g, meta, cnt, list, ovf);
  gather_kernel<<<E_N / 4 / 64, 256, 0, stream>>>(cnt, list, meta, c8g, W_sbf2,
                                                  down, alpha, ovf, xkj);
  epi_kernel<<<E_N / 64, 256, 0, stream>>>(x, x_ji, xkj, wupT, rb1T, rb1_b,
                                           rb2T, rb2_b, linT, b_lin,
                                           ra1T, ra1_b, ra2T, ra2_b,
                                           (float*)d_out);
}

// Round 6
// 330.198 us; speedup vs baseline: 1.2655x; 1.1770x over previous
//
#include <hip/hip_runtime.h>
#include <hip/hip_bf16.h>
#include <stdint.h>

typedef __bf16 bf16_t;
typedef bf16_t bf16x8 __attribute__((ext_vector_type(8)));
typedef bf16_t bf16x2 __attribute__((ext_vector_type(2)));
typedef float f32x4 __attribute__((ext_vector_type(4)));

#define E_N 65536
#define T_N 262144
#define CAP 16          // bucket capacity per edge (avg occupancy 4)
#define OVF_MAX T_N     // overflow list can hold every triplet -> always correct

__device__ __forceinline__ float silu_f(float v) {
  return v / (1.0f + __expf(-v));
}

// B-row permutation: LDS row r = tj*16+i holds real output column
// 32*(tj>>1) + 2*i + (tj&1), so each lane's acc[2g],acc[2g+1] are 2
// consecutive real columns -> bf16x2 stores everywhere.
__device__ __forceinline__ int permrow(int n) {
  return (n & ~31) | ((n & 1) << 4) | ((n & 30) >> 1);
}

__device__ __forceinline__ uint32_t pack_bf16(float a, float b) {
  union { bf16x2 h; uint32_t u; } u;
  u.h[0] = (bf16_t)a; u.h[1] = (bf16_t)b;
  return u.u;
}

// ---- MFMA tile GEMM on swizzled stride-128 LDS tiles ----
// element (row,k) stored at row*128 + (((k>>3) ^ (row&15))<<3) + (k&7)
template<int KI, int NTJ>
__device__ __forceinline__ void gemm_tile(const bf16_t* A, const bf16_t* B,
                                          int mb, int nb, int l16, int q,
                                          f32x4 (&acc)[2][NTJ]) {
#pragma unroll
  for (int kt = 0; kt < KI; ++kt) {
    const int sw = ((kt * 4 + q) ^ l16) << 3;
    bf16x8 a0 = *(const bf16x8*)(A + ((mb + l16) << 7) + sw);
    bf16x8 a1 = *(const bf16x8*)(A + ((mb + 16 + l16) << 7) + sw);
#pragma unroll
    for (int tj = 0; tj < NTJ; ++tj) {
      bf16x8 b = *(const bf16x8*)(B + ((nb + tj * 16 + l16) << 7) + sw);
      acc[0][tj] = __builtin_amdgcn_mfma_f32_16x16x32_bf16(a0, b, acc[0][tj], 0, 0, 0);
      acc[1][tj] = __builtin_amdgcn_mfma_f32_16x16x32_bf16(a1, b, acc[1][tj], 0, 0, 0);
    }
  }
}

// Load transposed bf16 weight [N][K] global -> perm'd+swizzled LDS.
template<int ROWS, int K8>
__device__ __forceinline__ void load_wT(bf16_t* dst, const bf16_t* src, int tid) {
  const uint4* s = (const uint4*)src;
#pragma unroll
  for (int i = tid; i < ROWS * K8; i += 256) {
    const int n = i / K8, k8 = i % K8;
    const int row = permrow(n);
    *(uint4*)(dst + (row << 7) + ((k8 ^ (row & 15)) << 3)) = s[i];
  }
}

// Stage fp32 [64][K] tile -> swizzled bf16 LDS. C4 = K/4.
template<int C4>
__device__ __forceinline__ void stage_x(bf16_t* dst, const float* src, int tid) {
  const float4* g = (const float4*)src;
#pragma unroll
  for (int i = tid; i < 64 * C4; i += 256) {
    const int row = i / C4, c4 = i % C4;
    float4 v = g[i];
    bf16_t t[4] = {(bf16_t)v.x, (bf16_t)v.y, (bf16_t)v.z, (bf16_t)v.w};
    *(uint2*)(dst + (row << 7) + ((((c4 >> 1) ^ (row & 15)) << 3) | ((c4 & 1) << 2))) =
        *(const uint2*)t;
  }
}

// =====================  K0: weight preprocessing + x-image build  ================
// Transpose all fp32 weights to bf16 [N][K]; fuse W_rbf1@W_rbf2 -> wcb[b][n][8];
// blocks >=115 build swizzled bf16 x-tile images (exact LDS layout, 16KB/tile).
__global__ void prep_kernel(
    const float* __restrict__ W_ji, const float* __restrict__ W_kj,
    const float* __restrict__ W_down, const float* __restrict__ W_up,
    const float* __restrict__ rb1, const float* __restrict__ rb2,
    const float* __restrict__ W_lin, const float* __restrict__ ra1,
    const float* __restrict__ ra2, const float* __restrict__ W_rbf1,
    const float* __restrict__ W_rbf2, const float* __restrict__ x,
    bf16_t* __restrict__ wjiT, bf16_t* __restrict__ wkjT,
    bf16_t* __restrict__ wdownT, bf16_t* __restrict__ wupT,
    bf16_t* __restrict__ rb1T, bf16_t* __restrict__ rb2T,
    bf16_t* __restrict__ linT, bf16_t* __restrict__ ra1T,
    bf16_t* __restrict__ ra2T, bf16_t* __restrict__ wcb,
    bf16_t* __restrict__ ximg)
{
  __shared__ __align__(16) bf16_t tile[64 * 128];
  const int tid = threadIdx.x;
  const int blk = blockIdx.x;

  if (blk >= 115) {        // x tile image: stage to LDS then dump linearly
    const int t = blk - 115;     // 0..1023
    stage_x<32>(tile, x + (size_t)t * 8192, tid);
    __syncthreads();
    uint4* dst = (uint4*)(ximg + (size_t)t * 8192);
    const uint4* s = (const uint4*)tile;
#pragma unroll
    for (int i = 0; i < 4; ++i) dst[i * 256 + tid] = s[i * 256 + tid];
    return;
  }
  if (blk >= 112) {
    const int o = (blk - 112) * 256 + tid;
    if (o < 640) {
      const int b = o >> 7, n = o & 127;
      bf16_t t[8];
#pragma unroll
      for (int r = 0; r < 6; ++r) {
        const float* w1 = W_rbf1 + (b + 1) * 48 + r * 8;
        const float* w2 = W_rbf2 + (b + 1) * 1024 + n;
        float s = 0.f;
#pragma unroll
        for (int c = 0; c < 8; ++c) s += w1[c] * w2[c * 128];
        t[r] = (bf16_t)s;
      }
      t[6] = (bf16_t)0.f; t[7] = (bf16_t)0.f;
      *(uint4*)(wcb + (b * 128 + n) * 8) = *(const uint4*)t;
    }
    return;
  }
  const int c = blk * 256 + tid;
  const float* src; bf16_t* dst; int n, k8, N, K;
  if (c < 22528) {
    const int m = c >> 11, w = c & 2047;
    n = w >> 4; k8 = w & 15; N = 128; K = 128;
    if (m == 0)      { src = W_ji;  dst = wjiT; }
    else if (m <= 5) { src = W_kj + m * 16384; dst = wkjT + (m - 1) * 16384; }
    else if (m == 6) { src = rb1;   dst = rb1T; }
    else if (m == 7) { src = rb2;   dst = rb2T; }
    else if (m == 8) { src = W_lin; dst = linT; }
    else if (m == 9) { src = ra1;   dst = ra1T; }
    else             { src = ra2;   dst = ra2T; }
  } else if (c < 27648) {
    const int m = (c - 22528) >> 10, w = (c - 22528) & 1023;
    n = w >> 4; k8 = w & 15; N = 64; K = 128;
    src = W_down + (m + 1) * 8192; dst = wdownT + m * 8192;
  } else {
    const int w = c - 27648;
    n = w >> 3; k8 = w & 7; N = 128; K = 64;
    src = W_up; dst = wupT;
  }
  bf16_t t[8];
#pragma unroll
  for (int j = 0; j < 8; ++j) t[j] = (bf16_t)src[(k8 * 8 + j) * N + n];
  *(uint4*)(dst + n * K + k8 * 8) = *(const uint4*)t;
}

// =====================  K1: edge-level GEMMs (branch-parallel)  =====================
// LDS 51.5 KB -> 3 blocks/CU; 3 barriers (tmp written in place into xA; Wdn
// reuses Wb's first half); x tile is a straight copy of the prebuilt image;
// rbf_p via 6-wide VALU dots (no padded MFMA tiles).
__global__ __launch_bounds__(256, 3)
void edge_kernel(const bf16_t* __restrict__ ximg, const float* __restrict__ rbf,
                 const float* __restrict__ b_kj, const float* __restrict__ b_ji,
                 const bf16_t* __restrict__ wjiT, const bf16_t* __restrict__ wkjT,
                 const bf16_t* __restrict__ wdownT, const bf16_t* __restrict__ wcb,
                 bf16_t* __restrict__ x_ji_out, bf16_t* __restrict__ down)
{
  __shared__ __align__(16) bf16_t xA[64 * 128];    // 16K; tmp overwrites in place
  __shared__ __align__(16) bf16_t Wb[128 * 128];   // 32K; Wdn reuses first 16K
  __shared__ __align__(16) bf16_t wcbS[128 * 8];   // 2K (this branch's slice)
  __shared__ __align__(16) bf16_t rbfS[64 * 8];    // 1K
  __shared__ float biasS[128];                     // 0.5K  -> total 52,736 B

  const int tid = threadIdx.x;
  const int lane = tid & 63, wv = tid >> 6;
  const int q = lane >> 4, l16 = lane & 15;
  const int mb = (wv >> 1) * 32, nb = (wv & 1) * 64;
  const int eb = blockIdx.x;
  const int br = eb % 6;           // 0 = x_ji, 1..5 = branch pipelines
  const int tile = eb / 6;         // 6 consecutive blocks share the x tile (L2)
  const int R = tile * 64;

  { // straight copy of prebuilt swizzled x image
    const uint4* s = (const uint4*)(ximg + (size_t)tile * 8192);
    uint4* d = (uint4*)xA;
#pragma unroll
    for (int i = 0; i < 4; ++i) d[i * 256 + tid] = s[i * 256 + tid];
  }
  if (br == 0) {
    load_wT<128, 16>(Wb, wjiT, tid);
    if (tid < 128) biasS[tid] = b_ji[tid];
  } else {
    load_wT<128, 16>(Wb, wkjT + (br - 1) * 16384, tid);
    if (tid < 128) biasS[tid] = b_kj[br * 128 + tid];
    if (tid >= 128)
      ((uint4*)wcbS)[tid - 128] =
          ((const uint4*)(wcb + (size_t)(br - 1) * 1024))[tid - 128];
    if (tid < 64) {
      const float* rg = rbf + (size_t)(R + tid) * 6;
      bf16_t t[8] = {(bf16_t)rg[0], (bf16_t)rg[1], (bf16_t)rg[2],
                     (bf16_t)rg[3], (bf16_t)rg[4], (bf16_t)rg[5],
                     (bf16_t)0.f, (bf16_t)0.f};
      *(uint4*)(rbfS + tid * 8) = *(const uint4*)t;
    }
  }
  __syncthreads();                              // barrier 1

  f32x4 acc[2][4] = {};
  gemm_tile<4, 4>(xA, Wb, mb, nb, l16, q, acc);

  if (br == 0) {
#pragma unroll
    for (int ti = 0; ti < 2; ++ti)
#pragma unroll
      for (int r = 0; r < 4; ++r) {
        const int row = mb + ti * 16 + q * 4 + r;
#pragma unroll
        for (int gl = 0; gl < 2; ++gl) {
          const int col0 = nb + gl * 32 + 2 * l16;
          const float2 b2 = *(const float2*)&biasS[col0];
          *(uint32_t*)&x_ji_out[(size_t)(R + row) * 128 + col0] =
              pack_bf16(silu_f(acc[ti][2 * gl][r] + b2.x),
                        silu_f(acc[ti][2 * gl + 1][r] + b2.y));
        }
      }
    return;
  }

  __syncthreads();                              // barrier 2: xA/Wb reads done

  load_wT<64, 16>(Wb, wdownT + (br - 1) * 8192, tid);   // Wdn -> Wb[0:16K]

  // rbf_p dots + tmp = silu(x@Wkj + b) * rbf_p  -> in place into xA
  float wc[2][2][6];
#pragma unroll
  for (int gl = 0; gl < 2; ++gl)
#pragma unroll
    for (int j = 0; j < 2; ++j) {
      const int col = nb + gl * 32 + 2 * l16 + j;
      bf16x8 w8 = *(const bf16x8*)&wcbS[col * 8];
#pragma unroll
      for (int c = 0; c < 6; ++c) wc[gl][j][c] = (float)w8[c];
    }
#pragma unroll
  for (int ti = 0; ti < 2; ++ti)
#pragma unroll
    for (int r = 0; r < 4; ++r) {
      const int row = mb + ti * 16 + q * 4 + r;
      bf16x8 rv8 = *(const bf16x8*)&rbfS[row * 8];
      float rv[6];
#pragma unroll
      for (int c = 0; c < 6; ++c) rv[c] = (float)rv8[c];
#pragma unroll
      for (int gl = 0; gl < 2; ++gl) {
        const int col0 = nb + gl * 32 + 2 * l16;
        const float2 b2 = *(const float2*)&biasS[col0];
        float p0 = 0.f, p1 = 0.f;
#pragma unroll
        for (int c = 0; c < 6; ++c) {
          p0 += rv[c] * wc[gl][0][c];
          p1 += rv[c] * wc[gl][1][c];
        }
        const float v0 = silu_f(acc[ti][2 * gl][r] + b2.x) * p0;
        const float v1 = silu_f(acc[ti][2 * gl + 1][r] + b2.y) * p1;
        *(uint32_t*)&xA[(row << 7) + ((((col0 >> 3) ^ (row & 15)) << 3) | (col0 & 7))] =
            pack_bf16(v0, v1);
      }
    }
  __syncthreads();                              // barrier 3

  const int nb2 = (wv & 1) * 32;
  f32x4 acc2[2][2] = {};
  gemm_tile<4, 2>(xA, Wb, mb, nb2, l16, q, acc2);
#pragma unroll
  for (int ti = 0; ti < 2; ++ti)
#pragma unroll
    for (int r = 0; r < 4; ++r) {
      const int row = mb + ti * 16 + q * 4 + r;
      const int col0 = nb2 + 2 * l16;
      *(uint32_t*)&down[((size_t)(br - 1) * E_N + R + row) * 64 + col0] =
          pack_bf16(silu_f(acc2[ti][0][r]), silu_f(acc2[ti][1][r]));
    }
}

// =====================  K2: triplet c8 projection + CSR bucket build  =====================
__global__ __launch_bounds__(256, 4)
void c8_kernel(const float* __restrict__ sbf, const int* __restrict__ idx_kj,
               const int* __restrict__ idx_ji, const int* __restrict__ bt,
               const float* __restrict__ Wsbf1,
               float* __restrict__ c8g, uint32_t* __restrict__ meta,
               int* __restrict__ cnt, int* __restrict__ list,
               int* __restrict__ ovf)   // ovf[0]=count, pairs (t,ji) from ovf[2]
{
  __shared__ float s_sbf[64 * 44];
  __shared__ float s_W1[2016];   // [6][42][8]
  __shared__ float s_c8[64 * 16];
  __shared__ int s_bs[64];

  const int tid = threadIdx.x;
  const int base = blockIdx.x * 64;

  for (int i = tid; i < 2016; i += 256) s_W1[i] = Wsbf1[i];
  if (tid < 64) {
    const int t = base + tid;
    const int kj = idx_kj[t];
    const int ji = idx_ji[t];
    const int bs = bt[kj] + 1;   // BT_LIST[b] = b-1 for b>=1; bt in [0,5)
    s_bs[tid] = bs;
    meta[t] = (uint32_t)kj | ((uint32_t)bs << 16);
    const int pos = atomicAdd(&cnt[ji], 1);
    if (pos < CAP) {
      list[ji * CAP + pos] = t;
    } else {
      const int o = atomicAdd(&ovf[0], 1);
      if (o < OVF_MAX) { ovf[2 + 2 * o] = t; ovf[2 + 2 * o + 1] = ji; }
    }
  }
  {
    const float2* sg = (const float2*)(sbf + (size_t)base * 42);
    for (int i = tid; i < 64 * 21; i += 256) {
      const int r = i / 21, c2 = i - r * 21;
      const float2 v = sg[i];
      s_sbf[r * 44 + c2 * 2] = v.x;
      s_sbf[r * 44 + c2 * 2 + 1] = v.y;
    }
  }
  __syncthreads();

  { // c8[i][brr*8+c] : brr=0 -> branch 5, brr=1 -> branch bs
    const int i = tid >> 2;
    const int brr = (tid >> 1) & 1;
    const int cg = tid & 1;
    const int b = brr ? s_bs[i] : 5;
    const float* w = &s_W1[b * 336 + cg * 4];
    const float* sb = &s_sbf[i * 44];
    float a0 = 0.f, a1 = 0.f, a2 = 0.f, a3 = 0.f;
#pragma unroll
    for (int s = 0; s < 42; ++s) {
      const float sv = sb[s];
      const float* ws = w + s * 8;
      a0 += sv * ws[0]; a1 += sv * ws[1]; a2 += sv * ws[2]; a3 += sv * ws[3];
    }
    float* dc = &s_c8[i * 16 + brr * 8 + cg * 4];
    dc[0] = a0; dc[1] = a1; dc[2] = a2; dc[3] = a3;
  }
  __syncthreads();

  { // coalesced write-out: 256 threads x float4 = 64 triplets x 16 floats
    const float4* s4 = (const float4*)s_c8;
    float4* g4 = (float4*)(c8g + (size_t)base * 16);
    g4[tid] = s4[tid];
  }
}

// =====================  K3: per-edge gather (no atomics)  =====================
__global__ __launch_bounds__(256, 8)
void gather_kernel(const int* __restrict__ cnt, const int* __restrict__ list,
                   const uint32_t* __restrict__ meta, const float* __restrict__ c8g,
                   const float* __restrict__ Wsbf2, const bf16_t* __restrict__ down,
                   const float* __restrict__ alpha_p, const int* __restrict__ ovf,
                   float* __restrict__ xkj)
{
  __shared__ float sW2[3072];   // [6][8][64]
  for (int i = threadIdx.x; i < 3072; i += 256) sW2[i] = Wsbf2[i];
  __syncthreads();

  const int e = blockIdx.x * 4 + (threadIdx.x >> 6);
  const int j = threadIdx.x & 63;
  const float alpha = alpha_p[0], oma = 1.f - alpha;
  const float* w5 = &sW2[5 * 512 + j];

  float acc = 0.f;
  int n = cnt[e];
  if (n > CAP) n = CAP;
#pragma unroll 2
  for (int k = 0; k < n; ++k) {
    const int t = __builtin_amdgcn_readfirstlane(list[e * CAP + k]);
    const uint32_t m = __builtin_amdgcn_readfirstlane(meta[t]);
    const int kj = m & 0xffff;
    const int b  = m >> 16;
    const float g5 = (float)down[((size_t)4 * E_N + kj) * 64 + j];
    const float gb = (float)down[((size_t)(b - 1) * E_N + kj) * 64 + j];
    const float* cp = c8g + (size_t)t * 16;
    float d5 = 0.f, db = 0.f;
#pragma unroll
    for (int c = 0; c < 8; ++c) {
      d5 += cp[c]     * w5[c * 64];
      db += cp[8 + c] * sW2[b * 512 + c * 64 + j];
    }
    acc += alpha * g5 * d5 + oma * gb * db;
  }

  const int oc = ovf[0];       // normally 0; full correctness fallback
  for (int k = 0; k < oc; ++k) {
    const int ji = ovf[2 + 2 * k + 1];
    if (ji != e) continue;
    const int t = ovf[2 + 2 * k];
    const uint32_t m = meta[t];
    const int kj = m & 0xffff;
    const int b  = m >> 16;
    const float g5 = (float)down[((size_t)4 * E_N + kj) * 64 + j];
    const float gb = (float)down[((size_t)(b - 1) * E_N + kj) * 64 + j];
    const float* cp = c8g + (size_t)t * 16;
    float d5 = 0.f, db = 0.f;
#pragma unroll
    for (int c = 0; c < 8; ++c) {
      d5 += cp[c]     * w5[c * 64];
      db += cp[8 + c] * sW2[b * 512 + c * 64 + j];
    }
    acc += alpha * g5 * d5 + oma * gb * db;
  }

  xkj[(size_t)e * 64 + j] = acc;
}

// =====================  K4: fused epilogue chain  =====================
__global__ __launch_bounds__(256, 2)
void epi_kernel(const float* __restrict__ x, const bf16_t* __restrict__ x_ji,
                const float* __restrict__ xkj,
                const bf16_t* __restrict__ wupT,
                const bf16_t* __restrict__ rb1T, const float* __restrict__ rb1_b,
                const bf16_t* __restrict__ rb2T, const float* __restrict__ rb2_b,
                const bf16_t* __restrict__ linT, const float* __restrict__ lin_b,
                const bf16_t* __restrict__ ra1T, const float* __restrict__ ra1_b,
                const bf16_t* __restrict__ ra2T, const float* __restrict__ ra2_b,
                float* __restrict__ out)
{
  __shared__ __align__(16) bf16_t bufA[64 * 128];
  __shared__ __align__(16) bf16_t bufB[64 * 128];
  __shared__ __align__(16) bf16_t Wb[128 * 128];
  __shared__ float biasS[128];

  const int tid = threadIdx.x;
  const int lane = tid & 63, wv = tid >> 6;
  const int q = lane >> 4, l16 = lane & 15;
  const int mb = (wv >> 1) * 32, nb = (wv & 1) * 64;
  const int R = blockIdx.x * 64;

  stage_x<16>(bufA, xkj + (size_t)R * 64, tid);
  load_wT<128, 8>(Wb, wupT, tid);
  __syncthreads();

  f32x4 hreg[2][4];
  { // h = x_ji + silu(xkj @ W_up)  -> bufB
    f32x4 acc[2][4] = {};
    gemm_tile<2, 4>(bufA, Wb, mb, nb, l16, q, acc);
#pragma unroll
    for (int ti = 0; ti < 2; ++ti)
#pragma unroll
      for (int r = 0; r < 4; ++r) {
        const int row = mb + ti * 16 + q * 4 + r;
#pragma unroll
        for (int gl = 0; gl < 2; ++gl) {
          const int col0 = nb + gl * 32 + 2 * l16;
          union { uint32_t u; bf16x2 h; } xj;
          xj.u = *(const uint32_t*)&x_ji[(size_t)(R + row) * 128 + col0];
          const float h0 = (float)xj.h[0] + silu_f(acc[ti][2 * gl][r]);
          const float h1 = (float)xj.h[1] + silu_f(acc[ti][2 * gl + 1][r]);
          hreg[ti][2 * gl][r] = h0;
          hreg[ti][2 * gl + 1][r] = h1;
          *(uint32_t*)&bufB[(row << 7) + ((((col0 >> 3) ^ (row & 15)) << 3) | (col0 & 7))] =
              pack_bf16(h0, h1);
        }
      }
  }

#define EPI_STAGE(ASRC, WSRC, BIAS, BODY)                                        \
  __syncthreads();                                                               \
  load_wT<128, 16>(Wb, WSRC, tid);                                               \
  if (tid < 128) biasS[tid] = BIAS[tid];                                         \
  __syncthreads();                                                               \
  {                                                                              \
    f32x4 acc[2][4] = {};                                                        \
    gemm_tile<4, 4>(ASRC, Wb, mb, nb, l16, q, acc);                              \
    _Pragma("unroll")                                                            \
    for (int ti = 0; ti < 2; ++ti)                                               \
      _Pragma("unroll")                                                          \
      for (int r = 0; r < 4; ++r) {                                              \
        const int row = mb + ti * 16 + q * 4 + r;                                \
        _Pragma("unroll")                                                        \
        for (int gl = 0; gl < 2; ++gl) {                                         \
          const int col0 = nb + gl * 32 + 2 * l16;                               \
          const float2 b2 = *(const float2*)&biasS[col0];                        \
          const float g0 = acc[ti][2 * gl][r] + b2.x;                            \
          const float g1 = acc[ti][2 * gl + 1][r] + b2.y;                        \
          BODY                                                                   \
        }                                                                        \
      }                                                                          \
  }

  // stage 1: u = silu(h @ rb1 + b) -> bufA
  EPI_STAGE(bufB, rb1T, rb1_b, {
    *(uint32_t*)&bufA[(row << 7) + ((((col0 >> 3) ^ (row & 15)) << 3) | (col0 & 7))] =
        pack_bf16(silu_f(g0), silu_f(g1));
  })

  // stage 2: h += silu(u @ rb2 + b) -> bufB
  EPI_STAGE(bufA, rb2T, rb2_b, {
    const float h0 = hreg[ti][2 * gl][r] + silu_f(g0);
    const float h1 = hreg[ti][2 * gl + 1][r] + silu_f(g1);
    hreg[ti][2 * gl][r] = h0; hreg[ti][2 * gl + 1][r] = h1;
    *(uint32_t*)&bufB[(row << 7) + ((((col0 >> 3) ^ (row & 15)) << 3) | (col0 & 7))] =
        pack_bf16(h0, h1);
  })

  // stage 3: h = silu(h @ W_lin + b) + x -> bufA
  EPI_STAGE(bufB, linT, lin_b, {
    const float2 xv = *(const float2*)&x[(size_t)(R + row) * 128 + col0];
    const float h0 = silu_f(g0) + xv.x;
    const float h1 = silu_f(g1) + xv.y;
    hreg[ti][2 * gl][r] = h0; hreg[ti][2 * gl + 1][r] = h1;
    *(uint32_t*)&bufA[(row << 7) + ((((col0 >> 3) ^ (row & 15)) << 3) | (col0 & 7))] =
        pack_bf16(h0, h1);
  })

  // stage 4: u = silu(h @ ra1 + b) -> bufB
  EPI_STAGE(bufA, ra1T, ra1_b, {
    *(uint32_t*)&bufB[(row << 7) + ((((col0 >> 3) ^ (row & 15)) << 3) | (col0 & 7))] =
        pack_bf16(silu_f(g0), silu_f(g1));
  })

  // stage 5: out = h + silu(u @ ra2 + b)
  EPI_STAGE(bufB, ra2T, ra2_b, {
    float2 o;
    o.x = hreg[ti][2 * gl][r] + silu_f(g0);
    o.y = hreg[ti][2 * gl + 1][r] + silu_f(g1);
    *(float2*)&out[(size_t)(R + row) * 128 + col0] = o;
  })
#undef EPI_STAGE
}

extern "C" void kernel_launch(void* const* d_in, const int* in_sizes, int n_in,
                              void* d_out, int out_size, void* d_ws, size_t ws_size,
                              hipStream_t stream)
{
  (void)in_sizes; (void)n_in; (void)out_size; (void)ws_size;
  const float* x      = (const float*)d_in[0];
  const float* rbf    = (const float*)d_in[1];
  const float* sbf    = (const float*)d_in[2];
  const int*   idx_kj = (const int*)d_in[3];
  const int*   idx_ji = (const int*)d_in[4];
  const int*   bt     = (const int*)d_in[5];
  const float* alpha  = (const float*)d_in[7];
  const float* W_kj   = (const float*)d_in[8];
  const float* b_kj   = (const float*)d_in[9];
  const float* W_rbf1 = (const float*)d_in[10];
  const float* W_rbf2 = (const float*)d_in[11];
  const float* W_sbf1 = (const float*)d_in[12];
  const float* W_sbf2 = (const float*)d_in[13];
  const float* W_down = (const float*)d_in[14];
  const float* W_ji   = (const float*)d_in[15];
  const float* b_ji   = (const float*)d_in[16];
  const float* W_up   = (const float*)d_in[17];
  const float* rb1_w  = (const float*)d_in[18];
  const float* rb1_b  = (const float*)d_in[19];
  const float* rb2_w  = (const float*)d_in[20];
  const float* rb2_b  = (const float*)d_in[21];
  const float* W_lin  = (const float*)d_in[22];
  const float* b_lin  = (const float*)d_in[23];
  const float* ra1_w  = (const float*)d_in[24];
  const float* ra1_b  = (const float*)d_in[25];
  const float* ra2_w  = (const float*)d_in[26];
  const float* ra2_b  = (const float*)d_in[27];

  char* ws = (char*)d_ws;
  bf16_t* down   = (bf16_t*)(ws);                 // 5*E*64*2  = 41,943,040
  bf16_t* x_ji   = (bf16_t*)(ws + 41943040);      // E*128*2   = 16,777,216
  float*  xkj    = (float*) (ws + 58720256);      // E*64*4    = 16,777,216
  char* wbase    = ws + 75497472;
  bf16_t* wjiT   = (bf16_t*)(wbase + 0);
  bf16_t* wkjT   = (bf16_t*)(wbase + 32768);
  bf16_t* wdownT = (bf16_t*)(wbase + 196608);
  bf16_t* wupT   = (bf16_t*)(wbase + 278528);
  bf16_t* rb1T   = (bf16_t*)(wbase + 294912);
  bf16_t* rb2T   = (bf16_t*)(wbase + 327680);
  bf16_t* linT   = (bf16_t*)(wbase + 360448);
  bf16_t* ra1T   = (bf16_t*)(wbase + 393216);
  bf16_t* ra2T   = (bf16_t*)(wbase + 425984);
  bf16_t* wcb    = (bf16_t*)(wbase + 458752);     // 5*128*8*2 = 10,240
  float*    c8g  = (float*)   (ws + 75966464);    // T*16*4    = 16,777,216
  uint32_t* meta = (uint32_t*)(ws + 92743680);    // T*4       =  1,048,576
  int*      list = (int*)     (ws + 93792256);    // E*CAP*4   =  4,194,304
  int*      cnt  = (int*)     (ws + 97986560);    // E*4       =    262,144
  int*      ovf  = (int*)     (ws + 98248704);    // 8 + 2*T*4 =  2,097,160
  // x-tile image aliases c8g: ximg is consumed by edge_kernel (before c8_kernel
  // writes c8g) -- stream-ordered, no overlap.
  bf16_t* ximg   = (bf16_t*)c8g;                  // E*128*2   = 16,777,216

  hipMemsetAsync(cnt, 0, 262144 + 8, stream);     // cnt + ovf[0..1]
  prep_kernel<<<1139, 256, 0, stream>>>(W_ji, W_kj, W_down, W_up, rb1_w, rb2_w,
                                        W_lin, ra1_w, ra2_w, W_rbf1, W_rbf2, x,
                                        wjiT, wkjT, wdownT, wupT, rb1T, rb2T,
                                        linT, ra1T, ra2T, wcb, ximg);
  edge_kernel<<<E_N / 64 * 6, 256, 0, stream>>>(ximg, rbf, b_kj, b_ji, wjiT,
                                                wkjT, wdownT, wcb, x_ji, down);
  c8_kernel<<<T_N / 64, 256, 0, stream>>>(sbf, idx_kj, idx_ji, bt, W_sbf1,
                                          c8g, meta, cnt, list, ovf);
  gather_kernel<<<E_N / 4 / 64, 256, 0, stream>>>(cnt, list, meta, c8g, W_sbf2,
                                                  down, alpha, ovf, xkj);
  epi_kernel<<<E_N / 64, 256, 0, stream>>>(x, x_ji, xkj, wupT, rb1T, rb1_b,
                                           rb2T, rb2_b, linT, b_lin,
                                           ra1T, ra1_b, ra2T, ra2_b,
                                           (float*)d_out);
}